// Round 1
// baseline (812.697 us; speedup 1.0000x reference)
//
#include <hip/hip_runtime.h>

// Discrete Radon transform via Fourier-slice identity: the reference's
// fft2 -> line-gather -> ifft collapses to exact integer shear-and-sum:
//   m in [0,512):   out[b,m,t].re = (1/sqrt(512)) * sum_y img[b, (t - m*y) & 511, y]
//   m in [512,768): out[b,m,t].re = (1/sqrt(512)) * sum_x img[b, x, (t - 2*(m-512)*x) & 511]
//   out[...,1] (imag) = 0 exactly.

#define NN 512
#define MU 768
#define TM 16          // angles per block
#define YT 16          // rows/cols staged per LDS stage
#define LDS_STRIDE 516 // 516 % 32 == 4 -> staging-transpose writes are <=2-way (free)

__global__ __launch_bounds__(512) void drt_main(const float* __restrict__ img,
                                                float* __restrict__ out) {
  __shared__ float rows[YT * LDS_STRIDE];

  const int b = blockIdx.y;
  const int tile = blockIdx.x;  // 0..31 -> case A (m=tile*16), 32..47 -> case B
  const int t = threadIdx.x;    // 0..511
  const bool caseB = (tile >= 32);
  const int a0 = caseB ? (tile - 32) * TM : tile * TM;
  const float* __restrict__ src = img + (size_t)b * (NN * NN);
  const int slope0 = caseB ? (2 * a0) : a0;
  const int dslope = caseB ? 2 : 1;

  float acc[TM];
#pragma unroll
  for (int i = 0; i < TM; ++i) acc[i] = 0.0f;

  for (int y0 = 0; y0 < NN; y0 += YT) {
    __syncthreads();
    if (caseB) {
      // stage 16 image rows: rows[r][j] = img[y0+r][j]
#pragma unroll
      for (int r = 0; r < YT; ++r) {
        rows[r * LDS_STRIDE + t] = src[(y0 + r) * NN + t];
      }
    } else {
      // stage 16 image columns, transposed: rows[c][x] = img[x][y0+c]
      // 64B-granular global reads (16 consecutive floats per row segment)
#pragma unroll
      for (int rep = 0; rep < YT; ++rep) {
        int idx = rep * NN + t;
        int x = idx >> 4;   // YT == 16
        int c = idx & 15;
        rows[c * LDS_STRIDE + x] = src[x * NN + y0 + c];
      }
    }
    __syncthreads();

#pragma unroll 4
    for (int r = 0; r < YT; ++r) {
      const int v = y0 + r;                 // y (case A) or x (case B)
      int base = t - slope0 * v;
      const int step = dslope * v;
      const float* __restrict__ rowp = rows + r * LDS_STRIDE;
#pragma unroll
      for (int i = 0; i < TM; ++i) {
        acc[i] += rowp[base & (NN - 1)];    // consecutive lanes -> consecutive banks
        base -= step;
      }
    }
  }

  const int m = caseB ? (NN + a0) : a0;
  const float scale = 0.04419417382415922f;  // 1/sqrt(512)
  float2* outp = (float2*)out;
#pragma unroll
  for (int i = 0; i < TM; ++i) {
    float2 vv;
    vv.x = acc[i] * scale;
    vv.y = 0.0f;  // ifft(fft(real line-sums)) has exactly zero imag part
    outp[((size_t)b * MU + (m + i)) * NN + t] = vv;
  }
}

extern "C" void kernel_launch(void* const* d_in, const int* in_sizes, int n_in,
                              void* d_out, int out_size, void* d_ws, size_t ws_size,
                              hipStream_t stream) {
  const float* img = (const float*)d_in[0];
  float* out = (float*)d_out;
  dim3 grid(48, 16);  // 32 case-A angle tiles + 16 case-B angle tiles, x 16 batches
  drt_main<<<grid, dim3(512), 0, stream>>>(img, out);
}

// Round 2
// 151.802 us; speedup vs baseline: 5.3537x; 5.3537x over previous
//
#include <hip/hip_runtime.h>

// Fast discrete Radon transform (exact, wrap-around shears):
//   case A (m<512):   R_m[t]   = sum_y img[(t - m*y) & 511, y]
//   case B (m>=512):  R'_a[t]  = sum_x img[x, (t - 2a*x) & 511], a = m-512
// out = R * (1/sqrt(512)), imag part exactly 0.
//
// Two-scale recursion (verified algebraically; q*h = 512):
//   D_q[c][w][x]   = sum_{u<q} A_{u*h+w}[(x - c*u*h) & 511]
//   D_{4q}[c''][w] = sum_{b<4} D_q[c'' mod q][w + b*h/4][(x - c''*b*h/4) & 511]
// Storage: class-major packed rows r = c*(h) + w. Case B keeps only even
// classes (256 rows, j = c/2). Stages: 1 ->(init, radix2) 2 ->(4 radix-4
// passes) 8 -> 32 -> 128 -> 512.

#define NN 512
#define MU 768
#define MASK 511
#define SCALE 0.04419417382415922f  // 1/sqrt(512)

// ---------------- init A: stage 1->2 with transpose (LDS-tiled) -----------
// outA[b][c'*256 + w][x] = img[b][x][w] + img[b][(x - c'*256)&511][w+256]
__global__ __launch_bounds__(256) void k_init_a(const float* __restrict__ img,
                                                float* __restrict__ outA) {
  __shared__ float T1[64][65], T2[64][65], T3[64][65];  // stride 65: conflict-free cols
  const int xt = blockIdx.x;            // x tile 0..7
  const int wt = blockIdx.y;            // w tile 0..3 (w' in [0,256))
  const int b  = blockIdx.z;
  const int x0 = xt * 64, w0 = wt * 64;
  const int x3 = ((xt + 4) & 7) * 64;   // (x - 256) & 511 tile
  const float* src = img + (size_t)b * NN * NN;
  for (int idx = threadIdx.x; idx < 64 * 64; idx += 256) {
    int rr = idx >> 6, cc = idx & 63;   // coalesced 256B row segments
    T1[rr][cc] = src[(x0 + rr) * NN + w0 + cc];
    T2[rr][cc] = src[(x0 + rr) * NN + w0 + 256 + cc];
    T3[rr][cc] = src[(x3 + rr) * NN + w0 + 256 + cc];
  }
  __syncthreads();
  float* dst = outA + (size_t)b * (512 * NN);
  for (int idx = threadIdx.x; idx < 64 * 64; idx += 256) {
    int wl = idx >> 6, xl = idx & 63;   // coalesced writes along x
    float t1 = T1[xl][wl];
    dst[(size_t)(w0 + wl) * NN + x0 + xl]       = t1 + T2[xl][wl];
    dst[(size_t)(256 + w0 + wl) * NN + x0 + xl] = t1 + T3[xl][wl];
  }
}

// ---------------- init B: stage 1->2, even class 0 only -------------------
// outB[b][w][x] = img[b][w][x] + img[b][w+256][x]
__global__ __launch_bounds__(512) void k_init_b(const float* __restrict__ img,
                                                float* __restrict__ outB) {
  const int w = blockIdx.x;   // 0..255
  const int b = blockIdx.y;
  const int x = threadIdx.x;
  const float* src = img + (size_t)b * NN * NN;
  outB[((size_t)b * 256 + w) * NN + x] = src[w * NN + x] + src[(w + 256) * NN + x];
}

// ---------------- radix-4 pass: stage q -> 4q -----------------------------
__global__ __launch_bounds__(512) void k_radix4(const float* __restrict__ inA,
                                                const float* __restrict__ inB,
                                                float* __restrict__ outA,
                                                float* __restrict__ outB,
                                                int lg_q) {
  const int r = blockIdx.x;        // 0..767: A rows 0..511, B rows 512..767
  const int b = blockIdx.y;
  const int x = threadIdx.x;
  const int lg_hh = 7 - lg_q;      // hh = h/4
  const int hh = 1 << lg_hh;
  const int h  = hh << 2;          // h = 512/q
  const int q  = 1 << lg_q;
  if (r < 512) {
    const float* in = inA + (size_t)b * (512 * NN);
    const int c2 = r >> lg_hh;               // c'' in [0,4q)
    const int w2 = r & (hh - 1);
    const int c  = c2 & (q - 1);             // c'' mod q
    const int base = c * h + w2;
    float s = 0.f;
#pragma unroll
    for (int bb = 0; bb < 4; ++bb) {
      int sh = (c2 * bb * hh) & MASK;
      s += in[(size_t)(base + bb * hh) * NN + ((x - sh) & MASK)];
    }
    outA[((size_t)b * 512 + r) * NN + x] = s;
  } else {
    const int rB = r - 512;                  // 0..255
    const float* in = inB + (size_t)b * (256 * NN);
    const int d  = rB >> lg_hh;              // d in [0,2q), class c'' = 2d
    const int w2 = rB & (hh - 1);
    const int jp = d & ((q >> 1) - 1);       // parent j = (2d mod q)/2
    const int base = jp * h + w2;
    float s = 0.f;
#pragma unroll
    for (int bb = 0; bb < 4; ++bb) {
      int sh = (d * bb * (hh << 1)) & MASK;  // (2d)*b*hh
      s += in[(size_t)(base + bb * hh) * NN + ((x - sh) & MASK)];
    }
    outB[((size_t)b * 256 + rB) * NN + x] = s;
  }
}

// ---------------- final: scale + interleave re/im -------------------------
__global__ __launch_bounds__(512) void k_final(const float* __restrict__ A,
                                               const float* __restrict__ Bb,
                                               float2* __restrict__ out) {
  const int r = blockIdx.x;  // 0..767
  const int b = blockIdx.y;
  const int t = threadIdx.x;
  float v = (r < 512) ? A[((size_t)b * 512 + r) * NN + t]
                      : Bb[((size_t)b * 256 + (r - 512)) * NN + t];
  float2 o; o.x = v * SCALE; o.y = 0.f;
  out[((size_t)b * MU + r) * NN + t] = o;
}

// ================= fallback: round-1 direct shear-sum =====================
#define TM 16
#define YT 16
#define LDS_STRIDE 516
__global__ __launch_bounds__(512) void drt_main(const float* __restrict__ img,
                                                float* __restrict__ out) {
  __shared__ float rows[YT * LDS_STRIDE];
  const int b = blockIdx.y;
  const int tile = blockIdx.x;
  const int t = threadIdx.x;
  const bool caseB = (tile >= 32);
  const int a0 = caseB ? (tile - 32) * TM : tile * TM;
  const float* __restrict__ src = img + (size_t)b * (NN * NN);
  const int slope0 = caseB ? (2 * a0) : a0;
  const int dslope = caseB ? 2 : 1;
  float acc[TM];
#pragma unroll
  for (int i = 0; i < TM; ++i) acc[i] = 0.0f;
  for (int y0 = 0; y0 < NN; y0 += YT) {
    __syncthreads();
    if (caseB) {
#pragma unroll
      for (int r = 0; r < YT; ++r) rows[r * LDS_STRIDE + t] = src[(y0 + r) * NN + t];
    } else {
#pragma unroll
      for (int rep = 0; rep < YT; ++rep) {
        int idx = rep * NN + t;
        int xx = idx >> 4, cc = idx & 15;
        rows[cc * LDS_STRIDE + xx] = src[xx * NN + y0 + cc];
      }
    }
    __syncthreads();
#pragma unroll 4
    for (int r = 0; r < YT; ++r) {
      const int v = y0 + r;
      int base = t - slope0 * v;
      const int step = dslope * v;
      const float* __restrict__ rowp = rows + r * LDS_STRIDE;
#pragma unroll
      for (int i = 0; i < TM; ++i) { acc[i] += rowp[base & MASK]; base -= step; }
    }
  }
  const int m = caseB ? (NN + a0) : a0;
  float2* outp = (float2*)out;
#pragma unroll
  for (int i = 0; i < TM; ++i) {
    float2 vv; vv.x = acc[i] * SCALE; vv.y = 0.0f;
    outp[((size_t)b * MU + (m + i)) * NN + t] = vv;
  }
}

extern "C" void kernel_launch(void* const* d_in, const int* in_sizes, int n_in,
                              void* d_out, int out_size, void* d_ws, size_t ws_size,
                              hipStream_t stream) {
  const float* img = (const float*)d_in[0];
  if (ws_size < (size_t)48 * 1024 * 1024) {
    // not enough scratch for the fast path
    drt_main<<<dim3(48, 16), dim3(512), 0, stream>>>(img, (float*)d_out);
    return;
  }
  float* W  = (float*)d_ws;
  float* A0 = W;                      // 16 x 512 x 512
  float* A1 = W + 4194304;
  float* B0 = W + 8388608;            // 16 x 256 x 512
  float* B1 = B0 + 2097152;

  k_init_a<<<dim3(8, 4, 16), dim3(256), 0, stream>>>(img, A0);
  k_init_b<<<dim3(256, 16), dim3(512), 0, stream>>>(img, B0);
  k_radix4<<<dim3(768, 16), dim3(512), 0, stream>>>(A0, B0, A1, B1, 1);  // 2->8
  k_radix4<<<dim3(768, 16), dim3(512), 0, stream>>>(A1, B1, A0, B0, 3);  // 8->32
  k_radix4<<<dim3(768, 16), dim3(512), 0, stream>>>(A0, B0, A1, B1, 5);  // 32->128
  k_radix4<<<dim3(768, 16), dim3(512), 0, stream>>>(A1, B1, A0, B0, 7);  // 128->512
  k_final<<<dim3(768, 16), dim3(512), 0, stream>>>(A0, B0, (float2*)d_out);
}

// Round 3
// 103.822 us; speedup vs baseline: 7.8278x; 1.4621x over previous
//
#include <hip/hip_runtime.h>

// Fast discrete Radon transform (exact, wrap-around shears), radix-16:
//   case A (m<512):   R_m[t]  = sum_y img[(t - m*y) & 511, y]
//   case B (m>=512):  R'_a[t] = sum_x img[x, (t - 2a*x) & 511], a = m-512
// out = R * (1/sqrt(512)), imag exactly 0.
//
// D_q[c][w][x] = sum_{u<q} A'[u*h+w][(x - c*u*h) & 511],  h = 512/q
// D_{16q}[C][w][x] = sum_{b<16} D_q[C mod q][w + b*H][(x - C*b*H) & 511]
// Stages: 1 ->(init, radix-2) 2 ->(radix-16) 32 ->(radix-16, fused output) 512.
// Case B keeps only even classes (256 rows).

#define NN 512
#define MU 768
#define MASK 511
#define SCALE 0.04419417382415922f  // 1/sqrt(512)

// ---- init: blocks 0..31 A (transpose + radix-2), 32..39 B (radix-2) ------
__global__ __launch_bounds__(256) void k_init(const float* __restrict__ img,
                                              float* __restrict__ A0,
                                              float* __restrict__ B0) {
  const int bx = blockIdx.x, b = blockIdx.y;
  const float* src = img + (size_t)b * NN * NN;
  if (bx < 32) {
    __shared__ float T1[64][65], T2[64][65], T3[64][65];
    const int xt = bx & 7, wt = bx >> 3;
    const int x0 = xt * 64, w0 = wt * 64, x3 = ((xt + 4) & 7) * 64;
    for (int idx = threadIdx.x; idx < 4096; idx += 256) {
      int rr = idx >> 6, cc = idx & 63;
      T1[rr][cc] = src[(x0 + rr) * NN + w0 + cc];
      T2[rr][cc] = src[(x0 + rr) * NN + w0 + 256 + cc];
      T3[rr][cc] = src[(x3 + rr) * NN + w0 + 256 + cc];
    }
    __syncthreads();
    float* dst = A0 + (size_t)b * (512 * NN);
    for (int idx = threadIdx.x; idx < 4096; idx += 256) {
      int wl = idx >> 6, xl = idx & 63;
      float t1 = T1[xl][wl];
      dst[(size_t)(w0 + wl) * NN + x0 + xl]       = t1 + T2[xl][wl];
      dst[(size_t)(256 + w0 + wl) * NN + x0 + xl] = t1 + T3[xl][wl];
    }
  } else {
    const int w0 = (bx - 32) * 32;  // 32 rows per block
    const float4* s4 = (const float4*)src;
    float4* d4 = (float4*)(B0 + (size_t)b * (256 * NN));
    for (int it = 0; it < 16; ++it) {
      int flat = it * 256 + threadIdx.x;  // 4096 float4 = 32 rows x 128
      int row = w0 + (flat >> 7), col = flat & 127;
      float4 u = s4[row * 128 + col], v = s4[(row + 256) * 128 + col];
      u.x += v.x; u.y += v.y; u.z += v.z; u.w += v.w;
      d4[row * 128 + col] = u;
    }
  }
}

// ---- pass 1: stage 2 -> 32 (H=16, shifts %16==0 -> float4 LDS reads) -----
__global__ __launch_bounds__(512) void k_pass1(const float* __restrict__ A0,
                                               const float* __restrict__ B0,
                                               float* __restrict__ A1,
                                               float* __restrict__ B1) {
  __shared__ float L[16 * 512];
  const int bx = blockIdx.x, b = blockIdx.y;
  const int t = threadIdx.x;
  const bool isB = bx >= 32;
  const int c = isB ? 0 : (bx >> 4);
  const int w = isB ? (bx - 32) : (bx & 15);
  const float* in = isB ? (B0 + (size_t)b * 256 * NN) : (A0 + (size_t)b * 512 * NN);
  {
    const float4* s4 = (const float4*)in;
    float4* l4 = (float4*)L;
    const int pbase = c * 256 + w;  // parent row bb: pbase + 16*bb
    for (int it = 0; it < 4; ++it) {
      int flat = it * 512 + t;      // 2048 float4
      int lrow = flat >> 7, col = flat & 127;
      l4[lrow * 128 + col] = s4[(pbase + 16 * lrow) * 128 + col];
    }
  }
  __syncthreads();
  const int g = t >> 7;            // 0..3
  const int x4 = (t & 127) * 4;
  float* outA = A1 + (size_t)b * 512 * NN;
  float* outB = B1 + (size_t)b * 256 * NN;
  for (int jj = 0; jj < 4; ++jj) {
    const int j = jj * 4 + g;
    const int C = isB ? (2 * j) : (c + 2 * j);
    float4 acc = {0.f, 0.f, 0.f, 0.f};
#pragma unroll
    for (int bb = 0; bb < 16; ++bb) {
      int base = (x4 - C * bb * 16) & MASK;  // %4==0: no wrap split
      float4 v = *(const float4*)&L[bb * 512 + base];
      acc.x += v.x; acc.y += v.y; acc.z += v.z; acc.w += v.w;
    }
    const int orow = isB ? (j * 16 + w) : (C * 16 + w);
    float* op = isB ? outB : outA;
    *(float4*)&op[(size_t)orow * NN + x4] = acc;
  }
}

// ---- pass 2: stage 32 -> 512 (H=1) + fused scale/float2 output -----------
__global__ __launch_bounds__(512) void k_pass2(const float* __restrict__ A1,
                                               const float* __restrict__ B1,
                                               float2* __restrict__ out) {
  __shared__ float L[16 * 512];
  const int bx = blockIdx.x, b = blockIdx.y;
  const int t = threadIdx.x;  // = x
  const bool isB = bx >= 32;
  const int c = isB ? 2 * (bx - 32) : bx;
  const float* in = isB ? (B1 + (size_t)b * 256 * NN + (size_t)(c >> 1) * 16 * NN)
                        : (A1 + (size_t)b * 512 * NN + (size_t)c * 16 * NN);
  {
    const float4* s4 = (const float4*)in;
    float4* l4 = (float4*)L;
    for (int it = 0; it < 4; ++it) l4[it * 512 + t] = s4[it * 512 + t];
  }
  __syncthreads();
  float acc[16];
#pragma unroll
  for (int j = 0; j < 16; ++j) acc[j] = 0.f;
#pragma unroll
  for (int bb = 0; bb < 16; ++bb) {
    int base = (t - c * bb) & MASK;
    const int step = (32 * bb) & MASK;
    const float* row = L + bb * 512;
#pragma unroll
    for (int j = 0; j < 16; ++j) {
      acc[j] += row[base];          // consecutive lanes -> consecutive banks
      base = (base - step) & MASK;  // shift for C = c + 32*(j+1)
    }
  }
#pragma unroll
  for (int j = 0; j < 16; ++j) {
    int m = isB ? (512 + (c >> 1) + 16 * j) : (c + 32 * j);
    float2 o; o.x = acc[j] * SCALE; o.y = 0.f;
    out[((size_t)b * MU + m) * NN + t] = o;
  }
}

// ================= fallback: round-1 direct shear-sum =====================
#define TM 16
#define YT 16
#define LDS_STRIDE 516
__global__ __launch_bounds__(512) void drt_main(const float* __restrict__ img,
                                                float* __restrict__ out) {
  __shared__ float rows[YT * LDS_STRIDE];
  const int b = blockIdx.y;
  const int tile = blockIdx.x;
  const int t = threadIdx.x;
  const bool caseB = (tile >= 32);
  const int a0 = caseB ? (tile - 32) * TM : tile * TM;
  const float* __restrict__ src = img + (size_t)b * (NN * NN);
  const int slope0 = caseB ? (2 * a0) : a0;
  const int dslope = caseB ? 2 : 1;
  float acc[TM];
#pragma unroll
  for (int i = 0; i < TM; ++i) acc[i] = 0.0f;
  for (int y0 = 0; y0 < NN; y0 += YT) {
    __syncthreads();
    if (caseB) {
#pragma unroll
      for (int r = 0; r < YT; ++r) rows[r * LDS_STRIDE + t] = src[(y0 + r) * NN + t];
    } else {
#pragma unroll
      for (int rep = 0; rep < YT; ++rep) {
        int idx = rep * NN + t;
        int xx = idx >> 4, cc = idx & 15;
        rows[cc * LDS_STRIDE + xx] = src[xx * NN + y0 + cc];
      }
    }
    __syncthreads();
#pragma unroll 4
    for (int r = 0; r < YT; ++r) {
      const int v = y0 + r;
      int base = t - slope0 * v;
      const int step = dslope * v;
      const float* __restrict__ rowp = rows + r * LDS_STRIDE;
#pragma unroll
      for (int i = 0; i < TM; ++i) { acc[i] += rowp[base & MASK]; base -= step; }
    }
  }
  const int m = caseB ? (NN + a0) : a0;
  float2* outp = (float2*)out;
#pragma unroll
  for (int i = 0; i < TM; ++i) {
    float2 vv; vv.x = acc[i] * SCALE; vv.y = 0.0f;
    outp[((size_t)b * MU + (m + i)) * NN + t] = vv;
  }
}

extern "C" void kernel_launch(void* const* d_in, const int* in_sizes, int n_in,
                              void* d_out, int out_size, void* d_ws, size_t ws_size,
                              hipStream_t stream) {
  const float* img = (const float*)d_in[0];
  if (ws_size < (size_t)51 * 1024 * 1024) {
    drt_main<<<dim3(48, 16), dim3(512), 0, stream>>>(img, (float*)d_out);
    return;
  }
  float* W  = (float*)d_ws;
  float* A0 = W;                 // 16 x 512 x 512
  float* A1 = W + 4194304;       // 16 x 512 x 512
  float* B0 = W + 8388608;       // 16 x 256 x 512
  float* B1 = W + 10485760;      // 16 x 256 x 512

  k_init <<<dim3(40, 16), dim3(256), 0, stream>>>(img, A0, B0);
  k_pass1<<<dim3(48, 16), dim3(512), 0, stream>>>(A0, B0, A1, B1);
  k_pass2<<<dim3(48, 16), dim3(512), 0, stream>>>(A1, B1, (float2*)d_out);
}